// Round 1
// 3136.625 us; speedup vs baseline: 1.3592x; 1.3592x over previous
//
#include <hip/hip_runtime.h>
#include <cmath>

#define N_LAYERS 24
#define D_MODEL 768
#define D_INNER 1536
#define D_STATE 16
#define DT_RANK 48
#define CONV_K 4
#define VOCAB 50280
#define SEQ 8
#define BATCH 64
#define NTOK (BATCH*SEQ)     /* 512 */
#define EPS 1e-5f
#define XZ_LD (2*D_INNER)    /* 3072 */
#define PROJ_LD (DT_RANK + 2*D_STATE) /* 80 */

typedef __attribute__((ext_vector_type(8))) __bf16 bf16x8;
typedef __attribute__((ext_vector_type(4))) float f32x4;

// ---------------- embedding gather ----------------
__global__ void embed_gather(const int* __restrict__ ids, const float* __restrict__ embed,
                             float* __restrict__ h) {
    int row = blockIdx.x;                 // token 0..511
    int b = row / SEQ, t = row % SEQ;
    int id = ids[b * 64 + t];             // full_ids is (64,64), take [:, :SEQ]
    const float4* src = (const float4*)(embed + (size_t)id * D_MODEL);
    float4* dst = (float4*)(h + (size_t)row * D_MODEL);
    dst[threadIdx.x] = src[threadIdx.x];  // 192 threads * 4 = 768
}

// ---------------- fp32 -> bf16 convert (grid-stride, vectorized) ----------------
__global__ void cvt_bf16_k(const float* __restrict__ in, __bf16* __restrict__ out, long n) {
    long i = ((long)blockIdx.x * blockDim.x + threadIdx.x) * 8;
    long stride = (long)gridDim.x * blockDim.x * 8;
    for (; i < n; i += stride) {
        float4 a = *(const float4*)(in + i);
        float4 b = *(const float4*)(in + i + 4);
        bf16x8 v;
        v[0]=(__bf16)a.x; v[1]=(__bf16)a.y; v[2]=(__bf16)a.z; v[3]=(__bf16)a.w;
        v[4]=(__bf16)b.x; v[5]=(__bf16)b.y; v[6]=(__bf16)b.z; v[7]=(__bf16)b.w;
        *(bf16x8*)(out + i) = v;
    }
}

// ---------------- rmsnorm (writes fp32 + bf16) ----------------
__global__ void rmsnorm_k(const float* __restrict__ x, const float* __restrict__ w,
                          float* __restrict__ out, __bf16* __restrict__ outb, int D) {
    int row = blockIdx.x;
    const float* xr = x + (size_t)row * D;
    float s = 0.f;
    for (int i = threadIdx.x; i < D; i += blockDim.x) { float v = xr[i]; s += v * v; }
    #pragma unroll
    for (int off = 32; off; off >>= 1) s += __shfl_down(s, off);
    __shared__ float red[8];
    int lane = threadIdx.x & 63, wid = threadIdx.x >> 6;
    if (lane == 0) red[wid] = s;
    __syncthreads();
    if (threadIdx.x == 0) {
        float tot = 0.f;
        for (int i = 0; i < (int)(blockDim.x >> 6); i++) tot += red[i];
        red[0] = rsqrtf(tot / (float)D + EPS);
    }
    __syncthreads();
    float r = red[0];
    for (int i = threadIdx.x; i < D; i += blockDim.x) {
        float v = xr[i] * r * w[i];
        out[(size_t)row * D + i] = v;
        outb[(size_t)row * D + i] = (__bf16)v;
    }
}

// ---------------- MFMA fp32-staged GEMM-BT (kept for dt: K=48) ----------------
#define LDSW 40   /* bf16 elems per LDS row: 32 data + 8 pad */
__global__ __launch_bounds__(256) void mgemm(
    const float* __restrict__ A, int lda,
    const float* __restrict__ B, int ldb,
    float* __restrict__ C, int ldc,
    int M, int N, int K, int KC,
    int epi, const float* __restrict__ bias)
{
    __shared__ __align__(16) __bf16 As[64 * LDSW];
    __shared__ __align__(16) __bf16 Bs[64 * LDSW];
    int tid = threadIdx.x;
    int m0 = blockIdx.y * 64, n0 = blockIdx.x * 64;
    int kstart = blockIdx.z * KC;
    int kend = kstart + KC; if (kend > K) kend = K;
    int wave = tid >> 6, lane = tid & 63;
    int l15 = lane & 15, quad = lane >> 4;
    int srow = tid >> 2;
    int skq  = (tid & 3) * 8;

    const float* Arow = A + (size_t)(m0 + srow) * lda;
    int brow = n0 + srow;
    const float* Brow = B + (size_t)brow * ldb;
    bool bvalid = brow < N;

    f32x4 acc[4];
    #pragma unroll
    for (int j = 0; j < 4; j++) acc[j] = (f32x4){0.f, 0.f, 0.f, 0.f};

    for (int k0 = kstart; k0 < kend; k0 += 32) {
        int kk = k0 + skq;
        __bf16* ad = &As[srow * LDSW + skq];
        if (kk + 8 <= K) {
            float4 a0 = *(const float4*)(Arow + kk);
            float4 a1 = *(const float4*)(Arow + kk + 4);
            ad[0] = (__bf16)a0.x; ad[1] = (__bf16)a0.y; ad[2] = (__bf16)a0.z; ad[3] = (__bf16)a0.w;
            ad[4] = (__bf16)a1.x; ad[5] = (__bf16)a1.y; ad[6] = (__bf16)a1.z; ad[7] = (__bf16)a1.w;
        } else {
            #pragma unroll
            for (int e = 0; e < 8; e++) ad[e] = (kk + e < K) ? (__bf16)Arow[kk + e] : (__bf16)0.f;
        }
        __bf16* bd = &Bs[srow * LDSW + skq];
        if (bvalid && kk + 8 <= K) {
            float4 b0 = *(const float4*)(Brow + kk);
            float4 b1 = *(const float4*)(Brow + kk + 4);
            bd[0] = (__bf16)b0.x; bd[1] = (__bf16)b0.y; bd[2] = (__bf16)b0.z; bd[3] = (__bf16)b0.w;
            bd[4] = (__bf16)b1.x; bd[5] = (__bf16)b1.y; bd[6] = (__bf16)b1.z; bd[7] = (__bf16)b1.w;
        } else {
            #pragma unroll
            for (int e = 0; e < 8; e++) bd[e] = (bvalid && kk + e < K) ? (__bf16)Brow[kk + e] : (__bf16)0.f;
        }
        __syncthreads();
        bf16x8 af = *(bf16x8*)&As[(wave * 16 + l15) * LDSW + quad * 8];
        #pragma unroll
        for (int j = 0; j < 4; j++) {
            bf16x8 bf = *(bf16x8*)&Bs[(j * 16 + l15) * LDSW + quad * 8];
            acc[j] = __builtin_amdgcn_mfma_f32_16x16x32_bf16(af, bf, acc[j], 0, 0, 0);
        }
        __syncthreads();
    }

    #pragma unroll
    for (int j = 0; j < 4; j++) {
        int n = n0 + j * 16 + l15;
        if (n >= N) continue;
        #pragma unroll
        for (int r = 0; r < 4; r++) {
            int m = m0 + wave * 16 + quad * 4 + r;
            float v = acc[j][r];
            size_t ci = (size_t)m * ldc + n;
            if (epi == 1) {
                v += bias[n];
                v = (v > 20.f) ? v : log1pf(expf(v));
                C[ci] = v;
            } else if (epi == 2) {
                C[ci] = C[ci] + v;
            } else if (epi == 3) {
                atomicAdd(&C[ci], v);
            } else {
                C[ci] = v;
            }
        }
    }
}

// ---------------- bf16-input GEMM-BT, BK=64: C[M,N] = A[M,K] @ B[N,K]^T ----------------
// A,B already bf16. K and KC must be multiples of 64, lda/ldb multiples of 8.
#define BLDSW 72   /* 64 data + 8 pad */
__global__ __launch_bounds__(256) void bgemm(
    const __bf16* __restrict__ A, int lda,
    const __bf16* __restrict__ B, int ldb,
    float* __restrict__ C, int ldc,
    int M, int N, int K, int KC,
    int epi, const float* __restrict__ bias)
{
    __shared__ __align__(16) __bf16 As[64 * BLDSW];
    __shared__ __align__(16) __bf16 Bs[64 * BLDSW];
    int tid = threadIdx.x;
    int m0 = blockIdx.y * 64, n0 = blockIdx.x * 64;
    int kstart = blockIdx.z * KC;
    int kend = kstart + KC; if (kend > K) kend = K;
    int wave = tid >> 6, lane = tid & 63;
    int l15 = lane & 15, quad = lane >> 4;
    int srow = tid >> 2;          // staging row 0..63
    int skq  = (tid & 3) * 16;    // 16 bf16 per thread per row

    const __bf16* Arow = A + (size_t)(m0 + srow) * lda;
    int brow = n0 + srow;
    const __bf16* Brow = B + (size_t)brow * ldb;
    bool bvalid = brow < N;

    f32x4 acc[4];
    #pragma unroll
    for (int j = 0; j < 4; j++) acc[j] = (f32x4){0.f, 0.f, 0.f, 0.f};

    for (int k0 = kstart; k0 < kend; k0 += 64) {
        int kk = k0 + skq;
        *(bf16x8*)&As[srow * BLDSW + skq]     = *(const bf16x8*)(Arow + kk);
        *(bf16x8*)&As[srow * BLDSW + skq + 8] = *(const bf16x8*)(Arow + kk + 8);
        __bf16* bd = &Bs[srow * BLDSW + skq];
        if (bvalid) {
            *(bf16x8*)bd       = *(const bf16x8*)(Brow + kk);
            *(bf16x8*)(bd + 8) = *(const bf16x8*)(Brow + kk + 8);
        } else {
            #pragma unroll
            for (int e = 0; e < 16; e++) bd[e] = (__bf16)0.f;
        }
        __syncthreads();
        #pragma unroll
        for (int kh = 0; kh < 2; kh++) {
            bf16x8 af = *(bf16x8*)&As[(wave * 16 + l15) * BLDSW + kh * 32 + quad * 8];
            #pragma unroll
            for (int j = 0; j < 4; j++) {
                bf16x8 bf = *(bf16x8*)&Bs[(j * 16 + l15) * BLDSW + kh * 32 + quad * 8];
                acc[j] = __builtin_amdgcn_mfma_f32_16x16x32_bf16(af, bf, acc[j], 0, 0, 0);
            }
        }
        __syncthreads();
    }

    #pragma unroll
    for (int j = 0; j < 4; j++) {
        int n = n0 + j * 16 + l15;
        if (n >= N) continue;
        #pragma unroll
        for (int r = 0; r < 4; r++) {
            int m = m0 + wave * 16 + quad * 4 + r;
            float v = acc[j][r];
            size_t ci = (size_t)m * ldc + n;
            if (epi == 1) {
                v += bias[n];
                v = (v > 20.f) ? v : log1pf(expf(v));
                C[ci] = v;
            } else if (epi == 3) {
                atomicAdd(&C[ci], v);
            } else {
                C[ci] = v;
            }
        }
    }
}

// ---------------- logits GEMM: A bf16 (512x768), B fp32 (embed), 4 m-tiles/block ----------------
// grid (ceil(N/64), 2). Each block: rows [m0, m0+256), cols [n0, n0+64). BK=32.
#define LLD 40
__global__ __launch_bounds__(256) void lgemm(
    const __bf16* __restrict__ A, int lda,
    const float* __restrict__ B, int ldb,
    float* __restrict__ C, int ldc,
    int N, int K)
{
    __shared__ __align__(16) __bf16 As[256 * LLD];
    __shared__ __align__(16) __bf16 Bs[64 * LLD];
    int tid = threadIdx.x;
    int wave = tid >> 6, lane = tid & 63;
    int l15 = lane & 15, quad = lane >> 4;
    int n0 = blockIdx.x * 64, m0 = blockIdx.y * 256;

    // A staging: 2 rows per thread, 16 cols each half
    int ar = tid >> 1;               // 0..127
    int ac = (tid & 1) * 16;         // 0 or 16
    const __bf16* Arow0 = A + (size_t)(m0 + ar) * lda;
    const __bf16* Arow1 = A + (size_t)(m0 + ar + 128) * lda;
    // B staging: fp32 -> bf16
    int srow = tid >> 2, skq = (tid & 3) * 8;
    int brow = n0 + srow;
    const float* Brow = B + (size_t)brow * ldb;
    bool bvalid = brow < N;

    f32x4 acc[4][4];
    #pragma unroll
    for (int mt = 0; mt < 4; mt++)
        #pragma unroll
        for (int j = 0; j < 4; j++) acc[mt][j] = (f32x4){0.f, 0.f, 0.f, 0.f};

    for (int k0 = 0; k0 < K; k0 += 32) {
        *(bf16x8*)&As[ar * LLD + ac]             = *(const bf16x8*)(Arow0 + k0 + ac);
        *(bf16x8*)&As[ar * LLD + ac + 8]         = *(const bf16x8*)(Arow0 + k0 + ac + 8);
        *(bf16x8*)&As[(ar + 128) * LLD + ac]     = *(const bf16x8*)(Arow1 + k0 + ac);
        *(bf16x8*)&As[(ar + 128) * LLD + ac + 8] = *(const bf16x8*)(Arow1 + k0 + ac + 8);
        __bf16* bd = &Bs[srow * LLD + skq];
        if (bvalid) {
            float4 b0 = *(const float4*)(Brow + k0 + skq);
            float4 b1 = *(const float4*)(Brow + k0 + skq + 4);
            bf16x8 bb;
            bb[0]=(__bf16)b0.x; bb[1]=(__bf16)b0.y; bb[2]=(__bf16)b0.z; bb[3]=(__bf16)b0.w;
            bb[4]=(__bf16)b1.x; bb[5]=(__bf16)b1.y; bb[6]=(__bf16)b1.z; bb[7]=(__bf16)b1.w;
            *(bf16x8*)bd = bb;
        } else {
            #pragma unroll
            for (int e = 0; e < 8; e++) bd[e] = (__bf16)0.f;
        }
        __syncthreads();
        bf16x8 bf[4];
        #pragma unroll
        for (int j = 0; j < 4; j++) bf[j] = *(bf16x8*)&Bs[(j * 16 + l15) * LLD + quad * 8];
        #pragma unroll
        for (int mt = 0; mt < 4; mt++) {
            bf16x8 af = *(bf16x8*)&As[(mt * 64 + wave * 16 + l15) * LLD + quad * 8];
            #pragma unroll
            for (int j = 0; j < 4; j++)
                acc[mt][j] = __builtin_amdgcn_mfma_f32_16x16x32_bf16(af, bf[j], acc[mt][j], 0, 0, 0);
        }
        __syncthreads();
    }

    #pragma unroll
    for (int mt = 0; mt < 4; mt++) {
        #pragma unroll
        for (int j = 0; j < 4; j++) {
            int n = n0 + j * 16 + l15;
            if (n >= N) continue;
            #pragma unroll
            for (int r = 0; r < 4; r++) {
                int m = m0 + mt * 64 + wave * 16 + quad * 4 + r;
                C[(size_t)m * ldc + n] = acc[mt][j][r];
            }
        }
    }
}

// ---------------- causal depthwise conv + bias + silu + mask (fp32 + bf16 out) ----------------
__global__ void conv_silu(const float* __restrict__ xz, const int* __restrict__ mask,
                          const float* __restrict__ cw, const float* __restrict__ cb,
                          float* __restrict__ xo, __bf16* __restrict__ xob)
{
    int idx = blockIdx.x * blockDim.x + threadIdx.x;
    if (idx >= NTOK * D_INNER) return;
    int d = idx % D_INNER;
    int row = idx / D_INNER;
    int t = row % SEQ, b = row / SEQ;
    float acc = cb[d];
    #pragma unroll
    for (int k = 0; k < CONV_K; k++) {
        int tt = t - (CONV_K - 1) + k;
        if (tt >= 0) {
            float xv = xz[(size_t)(b * SEQ + tt) * XZ_LD + d];
            float mf = (float)mask[b * 64 + tt];
            acc += xv * mf * cw[d * CONV_K + k];
        }
    }
    float mf = (float)mask[b * 64 + t];
    float sv = acc / (1.f + expf(-acc));
    float o = sv * mf;
    xo[(size_t)row * D_INNER + d] = o;
    xob[(size_t)row * D_INNER + d] = (__bf16)o;
}

// ---------------- selective scan + D-skip + z-gate (fp32 + bf16 out) ----------------
__global__ void scan_k(const float* __restrict__ xz, const float* __restrict__ xc,
                       const float* __restrict__ proj, const float* __restrict__ dt,
                       const float* __restrict__ A_log, const float* __restrict__ Dp,
                       float* __restrict__ y, __bf16* __restrict__ yb)
{
    int idx = blockIdx.x * blockDim.x + threadIdx.x;
    if (idx >= BATCH * D_INNER) return;
    int d = idx % D_INNER;
    int b = idx / D_INNER;
    float A[D_STATE];
    #pragma unroll
    for (int n = 0; n < D_STATE; n++) A[n] = -expf(A_log[d * D_STATE + n]);
    float Dv = Dp[d];
    float h[D_STATE];
    #pragma unroll
    for (int n = 0; n < D_STATE; n++) h[n] = 0.f;
    for (int t = 0; t < SEQ; t++) {
        int row = b * SEQ + t;
        float dtv = dt[(size_t)row * D_INNER + d];
        float xv = xc[(size_t)row * D_INNER + d];
        float yv = 0.f;
        #pragma unroll
        for (int n = 0; n < D_STATE; n++) {
            float dA = expf(dtv * A[n]);
            float Bv = proj[(size_t)row * PROJ_LD + DT_RANK + n];
            float Cv = proj[(size_t)row * PROJ_LD + DT_RANK + D_STATE + n];
            h[n] = dA * h[n] + dtv * Bv * xv;
            yv += h[n] * Cv;
        }
        yv += xv * Dv;
        float z = xz[(size_t)row * XZ_LD + D_INNER + d];
        yv *= z / (1.f + expf(-z));
        y[(size_t)row * D_INNER + d] = yv;
        yb[(size_t)row * D_INNER + d] = (__bf16)yv;
    }
}

extern "C" void kernel_launch(void* const* d_in, const int* in_sizes, int n_in,
                              void* d_out, int out_size, void* d_ws, size_t ws_size,
                              hipStream_t stream) {
    const int*   full_ids = (const int*)  d_in[0];
    const int*   full_mask= (const int*)  d_in[1];
    const float* embed    = (const float*)d_in[3];
    const float* norm_w   = (const float*)d_in[4];
    const float* in_w     = (const float*)d_in[5];
    const float* conv_w   = (const float*)d_in[6];
    const float* conv_b   = (const float*)d_in[7];
    const float* xp_w     = (const float*)d_in[8];
    const float* dtp_w    = (const float*)d_in[9];
    const float* dtp_b    = (const float*)d_in[10];
    const float* A_log    = (const float*)d_in[11];
    const float* Dp       = (const float*)d_in[12];
    const float* out_w    = (const float*)d_in[13];
    const float* norm_f_w = (const float*)d_in[14];
    float* out = (float*)d_out;

    char* ws = (char*)d_ws;
    size_t off = 0;
    auto allocb = [&](size_t nbytes) {
        void* p = (void*)(ws + off);
        off += ((nbytes + 255) / 256) * 256;
        return p;
    };
    float*  h    = (float*) allocb((size_t)NTOK * D_MODEL * 4);
    float*  hn   = (float*) allocb((size_t)NTOK * D_MODEL * 4);
    float*  xz   = (float*) allocb((size_t)NTOK * XZ_LD * 4);
    float*  xc   = (float*) allocb((size_t)NTOK * D_INNER * 4);
    float*  proj = (float*) allocb((size_t)NTOK * PROJ_LD * 4);
    float*  dt   = (float*) allocb((size_t)NTOK * D_INNER * 4);
    float*  y    = (float*) allocb((size_t)NTOK * D_INNER * 4);
    __bf16* hn_b = (__bf16*)allocb((size_t)NTOK * D_MODEL * 2);
    __bf16* xcb  = (__bf16*)allocb((size_t)NTOK * D_INNER * 2);
    __bf16* y_b  = (__bf16*)allocb((size_t)NTOK * D_INNER * 2);

    size_t w_inw = (size_t)N_LAYERS * 2 * D_INNER * D_MODEL * 2;
    size_t w_xpw = (size_t)N_LAYERS * PROJ_LD * D_INNER * 2;
    size_t w_ow  = (size_t)N_LAYERS * D_MODEL * D_INNER * 2;
    bool full = (ws_size >= off + w_inw + w_xpw + w_ow);

    __bf16 *in_w_b = nullptr, *xp_w_b = nullptr, *out_w_b = nullptr;
    if (full) {
        in_w_b  = (__bf16*)allocb(w_inw);
        xp_w_b  = (__bf16*)allocb(w_xpw);
        out_w_b = (__bf16*)allocb(w_ow);
        auto cvt = [&](const float* src, __bf16* dst, long n) {
            long g = (n / 8 + 255) / 256; if (g > 4096) g = 4096;
            cvt_bf16_k<<<(int)g, 256, 0, stream>>>(src, dst, n);
        };
        cvt(in_w,  in_w_b,  (long)N_LAYERS * 2 * D_INNER * D_MODEL);
        cvt(xp_w,  xp_w_b,  (long)N_LAYERS * PROJ_LD * D_INNER);
        cvt(out_w, out_w_b, (long)N_LAYERS * D_MODEL * D_INNER);
    }

    embed_gather<<<NTOK, 192, 0, stream>>>(full_ids, embed, h);

    for (int l = 0; l < N_LAYERS; l++) {
        const float* inw  = in_w  + (size_t)l * 2 * D_INNER * D_MODEL;
        const float* cw   = conv_w + (size_t)l * D_INNER * CONV_K;
        const float* cb   = conv_b + (size_t)l * D_INNER;
        const float* xpw  = xp_w  + (size_t)l * PROJ_LD * D_INNER;
        const float* dtw  = dtp_w + (size_t)l * D_INNER * DT_RANK;
        const float* dtb  = dtp_b + (size_t)l * D_INNER;
        const float* Al   = A_log + (size_t)l * D_INNER * D_STATE;
        const float* Dl   = Dp    + (size_t)l * D_INNER;
        const float* ow   = out_w + (size_t)l * D_MODEL * D_INNER;

        rmsnorm_k<<<NTOK, 256, 0, stream>>>(h, norm_w + (size_t)l * D_MODEL, hn, hn_b, D_MODEL);

        if (full) {
            const __bf16* inwb = in_w_b  + (size_t)l * 2 * D_INNER * D_MODEL;
            const __bf16* xpwb = xp_w_b  + (size_t)l * PROJ_LD * D_INNER;
            const __bf16* owb  = out_w_b + (size_t)l * D_MODEL * D_INNER;
            // xz = hn @ in_w^T   (512 x 3072, K=768)
            bgemm<<<dim3(2 * D_INNER / 64, NTOK / 64, 1), 256, 0, stream>>>(
                hn_b, D_MODEL, inwb, D_MODEL, xz, XZ_LD, NTOK, 2 * D_INNER, D_MODEL, D_MODEL, 0, nullptr);
            conv_silu<<<(NTOK * D_INNER + 255) / 256, 256, 0, stream>>>(xz, full_mask, cw, cb, xc, xcb);
            // proj = xc @ xp_w^T  (512 x 80, K=1536)
            bgemm<<<dim3((PROJ_LD + 63) / 64, NTOK / 64, 1), 256, 0, stream>>>(
                xcb, D_INNER, xpwb, D_INNER, proj, PROJ_LD, NTOK, PROJ_LD, D_INNER, D_INNER, 0, nullptr);
            // dt = softplus(proj[:, :48] @ dtp_w^T + dtp_b)  (K=48 -> fp32 path)
            mgemm<<<dim3(D_INNER / 64, NTOK / 64, 1), 256, 0, stream>>>(
                proj, PROJ_LD, dtw, DT_RANK, dt, D_INNER, NTOK, D_INNER, DT_RANK, DT_RANK, 1, dtb);
            scan_k<<<(BATCH * D_INNER + 255) / 256, 256, 0, stream>>>(xz, xc, proj, dt, Al, Dl, y, y_b);
            // h += y @ out_w^T  (split-K z=4, atomicAdd into residual h)
            bgemm<<<dim3(D_MODEL / 64, NTOK / 64, 4), 256, 0, stream>>>(
                y_b, D_INNER, owb, D_INNER, h, D_MODEL, NTOK, D_MODEL, D_INNER, 384, 3, nullptr);
        } else {
            mgemm<<<dim3(2 * D_INNER / 64, NTOK / 64, 1), 256, 0, stream>>>(
                hn, D_MODEL, inw, D_MODEL, xz, XZ_LD, NTOK, 2 * D_INNER, D_MODEL, D_MODEL, 0, nullptr);
            conv_silu<<<(NTOK * D_INNER + 255) / 256, 256, 0, stream>>>(xz, full_mask, cw, cb, xc, xcb);
            mgemm<<<dim3((PROJ_LD + 63) / 64, NTOK / 64, 1), 256, 0, stream>>>(
                xc, D_INNER, xpw, D_INNER, proj, PROJ_LD, NTOK, PROJ_LD, D_INNER, D_INNER, 0, nullptr);
            mgemm<<<dim3(D_INNER / 64, NTOK / 64, 1), 256, 0, stream>>>(
                proj, PROJ_LD, dtw, DT_RANK, dt, D_INNER, NTOK, D_INNER, DT_RANK, DT_RANK, 1, dtb);
            scan_k<<<(BATCH * D_INNER + 255) / 256, 256, 0, stream>>>(xz, xc, proj, dt, Al, Dl, y, y_b);
            mgemm<<<dim3(D_MODEL / 64, NTOK / 64, 4), 256, 0, stream>>>(
                y, D_INNER, ow, D_INNER, h, D_MODEL, NTOK, D_MODEL, D_INNER, 384, 3, nullptr);
        }
    }

    rmsnorm_k<<<NTOK, 256, 0, stream>>>(h, norm_f_w, hn, hn_b, D_MODEL);
    // logits = hn @ embed^T  (512 x 50280, K=768); 4 m-tiles/block, B streamed 2x
    lgemm<<<dim3((VOCAB + 63) / 64, 2, 1), 256, 0, stream>>>(
        hn_b, D_MODEL, embed, D_MODEL, out, VOCAB, VOCAB, D_MODEL);
}

// Round 2
// 2492.132 us; speedup vs baseline: 1.7107x; 1.2586x over previous
//
#include <hip/hip_runtime.h>
#include <cmath>

#define N_LAYERS 24
#define D_MODEL 768
#define D_INNER 1536
#define D_STATE 16
#define DT_RANK 48
#define CONV_K 4
#define VOCAB 50280
#define SEQ 8
#define BATCH 64
#define NTOK (BATCH*SEQ)     /* 512 */
#define EPS 1e-5f
#define XZ_LD (2*D_INNER)    /* 3072 */
#define PROJ_LD (DT_RANK + 2*D_STATE) /* 80 */

typedef __attribute__((ext_vector_type(8))) __bf16 bf16x8;
typedef __attribute__((ext_vector_type(4))) float f32x4;

// ---------------- embedding gather ----------------
__global__ void embed_gather(const int* __restrict__ ids, const float* __restrict__ embed,
                             float* __restrict__ h) {
    int row = blockIdx.x;
    int b = row / SEQ, t = row % SEQ;
    int id = ids[b * 64 + t];
    const float4* src = (const float4*)(embed + (size_t)id * D_MODEL);
    float4* dst = (float4*)(h + (size_t)row * D_MODEL);
    dst[threadIdx.x] = src[threadIdx.x];
}

// ---------------- fp32 -> bf16 convert ----------------
__global__ void cvt_bf16_k(const float* __restrict__ in, __bf16* __restrict__ out, long n) {
    long i = ((long)blockIdx.x * blockDim.x + threadIdx.x) * 8;
    long stride = (long)gridDim.x * blockDim.x * 8;
    for (; i < n; i += stride) {
        float4 a = *(const float4*)(in + i);
        float4 b = *(const float4*)(in + i + 4);
        bf16x8 v;
        v[0]=(__bf16)a.x; v[1]=(__bf16)a.y; v[2]=(__bf16)a.z; v[3]=(__bf16)a.w;
        v[4]=(__bf16)b.x; v[5]=(__bf16)b.y; v[6]=(__bf16)b.z; v[7]=(__bf16)b.w;
        *(bf16x8*)(out + i) = v;
    }
}

// ---------------- rmsnorm (writes fp32 + bf16) ----------------
__global__ void rmsnorm_k(const float* __restrict__ x, const float* __restrict__ w,
                          float* __restrict__ out, __bf16* __restrict__ outb, int D) {
    int row = blockIdx.x;
    const float* xr = x + (size_t)row * D;
    float s = 0.f;
    for (int i = threadIdx.x; i < D; i += blockDim.x) { float v = xr[i]; s += v * v; }
    #pragma unroll
    for (int off = 32; off; off >>= 1) s += __shfl_down(s, off);
    __shared__ float red[8];
    int lane = threadIdx.x & 63, wid = threadIdx.x >> 6;
    if (lane == 0) red[wid] = s;
    __syncthreads();
    if (threadIdx.x == 0) {
        float tot = 0.f;
        for (int i = 0; i < (int)(blockDim.x >> 6); i++) tot += red[i];
        red[0] = rsqrtf(tot / (float)D + EPS);
    }
    __syncthreads();
    float r = red[0];
    for (int i = threadIdx.x; i < D; i += blockDim.x) {
        float v = xr[i] * r * w[i];
        out[(size_t)row * D + i] = v;
        outb[(size_t)row * D + i] = (__bf16)v;
    }
}

// ---------------- MFMA fp32-staged GEMM-BT (kept for dt: K=48, and fallback) ----------------
#define LDSW 40
__global__ __launch_bounds__(256) void mgemm(
    const float* __restrict__ A, int lda,
    const float* __restrict__ B, int ldb,
    float* __restrict__ C, int ldc,
    int M, int N, int K, int KC,
    int epi, const float* __restrict__ bias)
{
    __shared__ __align__(16) __bf16 As[64 * LDSW];
    __shared__ __align__(16) __bf16 Bs[64 * LDSW];
    int tid = threadIdx.x;
    int m0 = blockIdx.y * 64, n0 = blockIdx.x * 64;
    int kstart = blockIdx.z * KC;
    int kend = kstart + KC; if (kend > K) kend = K;
    int wave = tid >> 6, lane = tid & 63;
    int l15 = lane & 15, quad = lane >> 4;
    int srow = tid >> 2;
    int skq  = (tid & 3) * 8;

    const float* Arow = A + (size_t)(m0 + srow) * lda;
    int brow = n0 + srow;
    const float* Brow = B + (size_t)brow * ldb;
    bool bvalid = brow < N;

    f32x4 acc[4];
    #pragma unroll
    for (int j = 0; j < 4; j++) acc[j] = (f32x4){0.f, 0.f, 0.f, 0.f};

    for (int k0 = kstart; k0 < kend; k0 += 32) {
        int kk = k0 + skq;
        __bf16* ad = &As[srow * LDSW + skq];
        if (kk + 8 <= K) {
            float4 a0 = *(const float4*)(Arow + kk);
            float4 a1 = *(const float4*)(Arow + kk + 4);
            ad[0] = (__bf16)a0.x; ad[1] = (__bf16)a0.y; ad[2] = (__bf16)a0.z; ad[3] = (__bf16)a0.w;
            ad[4] = (__bf16)a1.x; ad[5] = (__bf16)a1.y; ad[6] = (__bf16)a1.z; ad[7] = (__bf16)a1.w;
        } else {
            #pragma unroll
            for (int e = 0; e < 8; e++) ad[e] = (kk + e < K) ? (__bf16)Arow[kk + e] : (__bf16)0.f;
        }
        __bf16* bd = &Bs[srow * LDSW + skq];
        if (bvalid && kk + 8 <= K) {
            float4 b0 = *(const float4*)(Brow + kk);
            float4 b1 = *(const float4*)(Brow + kk + 4);
            bd[0] = (__bf16)b0.x; bd[1] = (__bf16)b0.y; bd[2] = (__bf16)b0.z; bd[3] = (__bf16)b0.w;
            bd[4] = (__bf16)b1.x; bd[5] = (__bf16)b1.y; bd[6] = (__bf16)b1.z; bd[7] = (__bf16)b1.w;
        } else {
            #pragma unroll
            for (int e = 0; e < 8; e++) bd[e] = (bvalid && kk + e < K) ? (__bf16)Brow[kk + e] : (__bf16)0.f;
        }
        __syncthreads();
        bf16x8 af = *(bf16x8*)&As[(wave * 16 + l15) * LDSW + quad * 8];
        #pragma unroll
        for (int j = 0; j < 4; j++) {
            bf16x8 bfv = *(bf16x8*)&Bs[(j * 16 + l15) * LDSW + quad * 8];
            acc[j] = __builtin_amdgcn_mfma_f32_16x16x32_bf16(af, bfv, acc[j], 0, 0, 0);
        }
        __syncthreads();
    }

    #pragma unroll
    for (int j = 0; j < 4; j++) {
        int n = n0 + j * 16 + l15;
        if (n >= N) continue;
        #pragma unroll
        for (int r = 0; r < 4; r++) {
            int m = m0 + wave * 16 + quad * 4 + r;
            float v = acc[j][r];
            size_t ci = (size_t)m * ldc + n;
            if (epi == 1) {
                v += bias[n];
                v = (v > 20.f) ? v : log1pf(expf(v));
                C[ci] = v;
            } else if (epi == 2) {
                C[ci] = C[ci] + v;
            } else if (epi == 3) {
                atomicAdd(&C[ci], v);
            } else {
                C[ci] = v;
            }
        }
    }
}

// ---------------- bf16 GEMM-BT v2: no As (direct L2 A-frags), double-buffered Bs ----------------
// One barrier per k-step; B/A for step k+1 prefetched into regs during step k's MFMAs.
// K, KC multiples of 64. M multiple of 64.
#define BLDSW 72
__global__ __launch_bounds__(256) void bgemm(
    const __bf16* __restrict__ A, int lda,
    const __bf16* __restrict__ B, int ldb,
    float* __restrict__ C, int ldc,
    int M, int N, int K, int KC,
    int epi, const float* __restrict__ bias)
{
    __shared__ __align__(16) __bf16 Bs[2][64 * BLDSW];
    int tid = threadIdx.x;
    int m0 = blockIdx.y * 64, n0 = blockIdx.x * 64;
    int kstart = blockIdx.z * KC;
    int kend = kstart + KC; if (kend > K) kend = K;
    int nsteps = (kend - kstart) >> 6;
    int wave = tid >> 6, lane = tid & 63;
    int l15 = lane & 15, quad = lane >> 4;
    int srow = tid >> 2;          // staging row 0..63
    int skq  = (tid & 3) * 16;    // 16 bf16 per thread

    const __bf16* Brow = B + (size_t)(n0 + srow) * ldb;
    bool bvalid = (n0 + srow) < N;
    const __bf16* Arow = A + (size_t)(m0 + wave * 16 + l15) * lda + quad * 8;

    f32x4 acc[4];
    #pragma unroll
    for (int j = 0; j < 4; j++) acc[j] = (f32x4){0.f, 0.f, 0.f, 0.f};

    bf16x8 zr;
    #pragma unroll
    for (int e = 0; e < 8; e++) zr[e] = (__bf16)0.f;

    bf16x8 pb0 = zr, pb1 = zr, pa0, pa1, a0v, a1v;

    int kk = kstart;
    if (bvalid) { pb0 = *(const bf16x8*)(Brow + kk + skq); pb1 = *(const bf16x8*)(Brow + kk + skq + 8); }
    a0v = *(const bf16x8*)(Arow + kk);
    a1v = *(const bf16x8*)(Arow + kk + 32);
    *(bf16x8*)&Bs[0][srow * BLDSW + skq]     = pb0;
    *(bf16x8*)&Bs[0][srow * BLDSW + skq + 8] = pb1;
    pb0 = zr; pb1 = zr;
    if (nsteps > 1) {
        kk = kstart + 64;
        if (bvalid) { pb0 = *(const bf16x8*)(Brow + kk + skq); pb1 = *(const bf16x8*)(Brow + kk + skq + 8); }
        pa0 = *(const bf16x8*)(Arow + kk);
        pa1 = *(const bf16x8*)(Arow + kk + 32);
    }
    __syncthreads();

    int cur = 0;
    for (int ks = 0; ks < nsteps; ks++) {
        #pragma unroll
        for (int kh = 0; kh < 2; kh++) {
            bf16x8 af = kh ? a1v : a0v;
            #pragma unroll
            for (int j = 0; j < 4; j++) {
                bf16x8 bfv = *(bf16x8*)&Bs[cur][(j * 16 + l15) * BLDSW + kh * 32 + quad * 8];
                acc[j] = __builtin_amdgcn_mfma_f32_16x16x32_bf16(af, bfv, acc[j], 0, 0, 0);
            }
        }
        if (ks + 1 < nsteps) {
            *(bf16x8*)&Bs[cur ^ 1][srow * BLDSW + skq]     = pb0;
            *(bf16x8*)&Bs[cur ^ 1][srow * BLDSW + skq + 8] = pb1;
            a0v = pa0; a1v = pa1;
            if (ks + 2 < nsteps) {
                kk = kstart + (ks + 2) * 64;
                if (bvalid) { pb0 = *(const bf16x8*)(Brow + kk + skq); pb1 = *(const bf16x8*)(Brow + kk + skq + 8); }
                pa0 = *(const bf16x8*)(Arow + kk);
                pa1 = *(const bf16x8*)(Arow + kk + 32);
            }
            __syncthreads();
            cur ^= 1;
        }
    }

    #pragma unroll
    for (int j = 0; j < 4; j++) {
        int n = n0 + j * 16 + l15;
        if (n >= N) continue;
        #pragma unroll
        for (int r = 0; r < 4; r++) {
            int m = m0 + wave * 16 + quad * 4 + r;
            float v = acc[j][r];
            size_t ci = (size_t)m * ldc + n;
            if (epi == 1) {
                v += bias[n];
                v = (v > 20.f) ? v : log1pf(expf(v));
                C[ci] = v;
            } else if (epi == 3) {
                atomicAdd(&C[ci], v);
            } else {
                C[ci] = v;
            }
        }
    }
}

// ---------------- logits GEMM v2: no As, double-buffered Bs, reg prefetch ----------------
// A bf16 (512x768), B fp32 (VOCAB x 768). grid (ceil(N/64), 2). m-tile 256, BK=32.
#define LLD 40
__global__ __launch_bounds__(256) void lgemm(
    const __bf16* __restrict__ A, int lda,
    const float* __restrict__ B, int ldb,
    float* __restrict__ C, int ldc,
    int N, int K)
{
    __shared__ __align__(16) __bf16 Bs[2][64 * LLD];
    int tid = threadIdx.x;
    int wave = tid >> 6, lane = tid & 63;
    int l15 = lane & 15, quad = lane >> 4;
    int n0 = blockIdx.x * 64, m0 = blockIdx.y * 256;

    int srow = tid >> 2, skq = (tid & 3) * 8;
    const float* Brow = B + (size_t)(n0 + srow) * ldb + skq;
    bool bvalid = (n0 + srow) < N;

    const __bf16* Abase = A + (size_t)(m0 + wave * 16 + l15) * lda + quad * 8;
    const size_t astr = (size_t)64 * lda;

    f32x4 acc[4][4];
    #pragma unroll
    for (int mt = 0; mt < 4; mt++)
        #pragma unroll
        for (int j = 0; j < 4; j++) acc[mt][j] = (f32x4){0.f, 0.f, 0.f, 0.f};

    int nsteps = K / 32;
    float4 nb0 = {0.f,0.f,0.f,0.f}, nb1 = {0.f,0.f,0.f,0.f};
    bf16x8 acur[4], anx[4];

    // k=0
    if (bvalid) { nb0 = *(const float4*)(Brow); nb1 = *(const float4*)(Brow + 4); }
    #pragma unroll
    for (int mt = 0; mt < 4; mt++) acur[mt] = *(const bf16x8*)(Abase + mt * astr);
    {
        bf16x8 bb;
        bb[0]=(__bf16)nb0.x; bb[1]=(__bf16)nb0.y; bb[2]=(__bf16)nb0.z; bb[3]=(__bf16)nb0.w;
        bb[4]=(__bf16)nb1.x; bb[5]=(__bf16)nb1.y; bb[6]=(__bf16)nb1.z; bb[7]=(__bf16)nb1.w;
        *(bf16x8*)&Bs[0][srow * LLD + skq] = bb;
    }
    nb0 = (float4){0.f,0.f,0.f,0.f}; nb1 = (float4){0.f,0.f,0.f,0.f};
    // prefetch k=1
    if (bvalid) { nb0 = *(const float4*)(Brow + 32); nb1 = *(const float4*)(Brow + 36); }
    #pragma unroll
    for (int mt = 0; mt < 4; mt++) anx[mt] = *(const bf16x8*)(Abase + mt * astr + 32);
    __syncthreads();

    int cur = 0;
    for (int ks = 0; ks < nsteps; ks++) {
        bf16x8 bfv[4];
        #pragma unroll
        for (int j = 0; j < 4; j++)
            bfv[j] = *(bf16x8*)&Bs[cur][(j * 16 + l15) * LLD + quad * 8];
        #pragma unroll
        for (int mt = 0; mt < 4; mt++)
            #pragma unroll
            for (int j = 0; j < 4; j++)
                acc[mt][j] = __builtin_amdgcn_mfma_f32_16x16x32_bf16(acur[mt], bfv[j], acc[mt][j], 0, 0, 0);
        if (ks + 1 < nsteps) {
            bf16x8 bb;
            bb[0]=(__bf16)nb0.x; bb[1]=(__bf16)nb0.y; bb[2]=(__bf16)nb0.z; bb[3]=(__bf16)nb0.w;
            bb[4]=(__bf16)nb1.x; bb[5]=(__bf16)nb1.y; bb[6]=(__bf16)nb1.z; bb[7]=(__bf16)nb1.w;
            *(bf16x8*)&Bs[cur ^ 1][srow * LLD + skq] = bb;
            #pragma unroll
            for (int mt = 0; mt < 4; mt++) acur[mt] = anx[mt];
            if (ks + 2 < nsteps) {
                int kk = (ks + 2) * 32;
                if (bvalid) { nb0 = *(const float4*)(Brow + kk); nb1 = *(const float4*)(Brow + kk + 4); }
                #pragma unroll
                for (int mt = 0; mt < 4; mt++) anx[mt] = *(const bf16x8*)(Abase + mt * astr + kk);
            }
            __syncthreads();
            cur ^= 1;
        }
    }

    #pragma unroll
    for (int mt = 0; mt < 4; mt++) {
        #pragma unroll
        for (int j = 0; j < 4; j++) {
            int n = n0 + j * 16 + l15;
            if (n >= N) continue;
            #pragma unroll
            for (int r = 0; r < 4; r++) {
                int m = m0 + mt * 64 + wave * 16 + quad * 4 + r;
                C[(size_t)m * ldc + n] = acc[mt][j][r];
            }
        }
    }
}

// ---------------- causal depthwise conv + bias + silu + mask (+ proj zero-fill) ----------------
__global__ void conv_silu(const float* __restrict__ xz, const int* __restrict__ mask,
                          const float* __restrict__ cw, const float* __restrict__ cb,
                          float* __restrict__ xo, __bf16* __restrict__ xob,
                          float* __restrict__ proj)
{
    int idx = blockIdx.x * blockDim.x + threadIdx.x;
    if (idx < NTOK * PROJ_LD) proj[idx] = 0.f;   // pre-zero for split-K atomicAdd
    if (idx >= NTOK * D_INNER) return;
    int d = idx % D_INNER;
    int row = idx / D_INNER;
    int t = row % SEQ, b = row / SEQ;
    float acc = cb[d];
    #pragma unroll
    for (int k = 0; k < CONV_K; k++) {
        int tt = t - (CONV_K - 1) + k;
        if (tt >= 0) {
            float xv = xz[(size_t)(b * SEQ + tt) * XZ_LD + d];
            float mf = (float)mask[b * 64 + tt];
            acc += xv * mf * cw[d * CONV_K + k];
        }
    }
    float mf = (float)mask[b * 64 + t];
    float sv = acc / (1.f + expf(-acc));
    float o = sv * mf;
    xo[(size_t)row * D_INNER + d] = o;
    xob[(size_t)row * D_INNER + d] = (__bf16)o;
}

// ---------------- selective scan + D-skip + z-gate ----------------
__global__ void scan_k(const float* __restrict__ xz, const float* __restrict__ xc,
                       const float* __restrict__ proj, const float* __restrict__ dt,
                       const float* __restrict__ A_log, const float* __restrict__ Dp,
                       float* __restrict__ y, __bf16* __restrict__ yb)
{
    int idx = blockIdx.x * blockDim.x + threadIdx.x;
    if (idx >= BATCH * D_INNER) return;
    int d = idx % D_INNER;
    int b = idx / D_INNER;
    float A[D_STATE];
    #pragma unroll
    for (int n = 0; n < D_STATE; n++) A[n] = -expf(A_log[d * D_STATE + n]);
    float Dv = Dp[d];
    float h[D_STATE];
    #pragma unroll
    for (int n = 0; n < D_STATE; n++) h[n] = 0.f;
    for (int t = 0; t < SEQ; t++) {
        int row = b * SEQ + t;
        float dtv = dt[(size_t)row * D_INNER + d];
        float xv = xc[(size_t)row * D_INNER + d];
        float yv = 0.f;
        #pragma unroll
        for (int n = 0; n < D_STATE; n++) {
            float dA = expf(dtv * A[n]);
            float Bv = proj[(size_t)row * PROJ_LD + DT_RANK + n];
            float Cv = proj[(size_t)row * PROJ_LD + DT_RANK + D_STATE + n];
            h[n] = dA * h[n] + dtv * Bv * xv;
            yv += h[n] * Cv;
        }
        yv += xv * Dv;
        float z = xz[(size_t)row * XZ_LD + D_INNER + d];
        yv *= z / (1.f + expf(-z));
        y[(size_t)row * D_INNER + d] = yv;
        yb[(size_t)row * D_INNER + d] = (__bf16)yv;
    }
}

extern "C" void kernel_launch(void* const* d_in, const int* in_sizes, int n_in,
                              void* d_out, int out_size, void* d_ws, size_t ws_size,
                              hipStream_t stream) {
    const int*   full_ids = (const int*)  d_in[0];
    const int*   full_mask= (const int*)  d_in[1];
    const float* embed    = (const float*)d_in[3];
    const float* norm_w   = (const float*)d_in[4];
    const float* in_w     = (const float*)d_in[5];
    const float* conv_w   = (const float*)d_in[6];
    const float* conv_b   = (const float*)d_in[7];
    const float* xp_w     = (const float*)d_in[8];
    const float* dtp_w    = (const float*)d_in[9];
    const float* dtp_b    = (const float*)d_in[10];
    const float* A_log    = (const float*)d_in[11];
    const float* Dp       = (const float*)d_in[12];
    const float* out_w    = (const float*)d_in[13];
    const float* norm_f_w = (const float*)d_in[14];
    float* out = (float*)d_out;

    char* ws = (char*)d_ws;
    size_t off = 0;
    auto allocb = [&](size_t nbytes) {
        void* p = (void*)(ws + off);
        off += ((nbytes + 255) / 256) * 256;
        return p;
    };
    float*  h    = (float*) allocb((size_t)NTOK * D_MODEL * 4);
    float*  hn   = (float*) allocb((size_t)NTOK * D_MODEL * 4);
    float*  xz   = (float*) allocb((size_t)NTOK * XZ_LD * 4);
    float*  xc   = (float*) allocb((size_t)NTOK * D_INNER * 4);
    float*  proj = (float*) allocb((size_t)NTOK * PROJ_LD * 4);
    float*  dt   = (float*) allocb((size_t)NTOK * D_INNER * 4);
    float*  y    = (float*) allocb((size_t)NTOK * D_INNER * 4);
    __bf16* hn_b = (__bf16*)allocb((size_t)NTOK * D_MODEL * 2);
    __bf16* xcb  = (__bf16*)allocb((size_t)NTOK * D_INNER * 2);
    __bf16* y_b  = (__bf16*)allocb((size_t)NTOK * D_INNER * 2);

    size_t w_inw = (size_t)N_LAYERS * 2 * D_INNER * D_MODEL * 2;
    size_t w_xpw = (size_t)N_LAYERS * PROJ_LD * D_INNER * 2;
    size_t w_ow  = (size_t)N_LAYERS * D_MODEL * D_INNER * 2;
    bool full = (ws_size >= off + w_inw + w_xpw + w_ow);

    __bf16 *in_w_b = nullptr, *xp_w_b = nullptr, *out_w_b = nullptr;
    if (full) {
        in_w_b  = (__bf16*)allocb(w_inw);
        xp_w_b  = (__bf16*)allocb(w_xpw);
        out_w_b = (__bf16*)allocb(w_ow);
        auto cvt = [&](const float* src, __bf16* dst, long n) {
            long g = (n / 8 + 255) / 256; if (g > 4096) g = 4096;
            cvt_bf16_k<<<(int)g, 256, 0, stream>>>(src, dst, n);
        };
        cvt(in_w,  in_w_b,  (long)N_LAYERS * 2 * D_INNER * D_MODEL);
        cvt(xp_w,  xp_w_b,  (long)N_LAYERS * PROJ_LD * D_INNER);
        cvt(out_w, out_w_b, (long)N_LAYERS * D_MODEL * D_INNER);
    }

    embed_gather<<<NTOK, 192, 0, stream>>>(full_ids, embed, h);

    for (int l = 0; l < N_LAYERS; l++) {
        const float* cw   = conv_w + (size_t)l * D_INNER * CONV_K;
        const float* cb   = conv_b + (size_t)l * D_INNER;
        const float* dtw  = dtp_w + (size_t)l * D_INNER * DT_RANK;
        const float* dtb  = dtp_b + (size_t)l * D_INNER;
        const float* Al   = A_log + (size_t)l * D_INNER * D_STATE;
        const float* Dl   = Dp    + (size_t)l * D_INNER;

        rmsnorm_k<<<NTOK, 256, 0, stream>>>(h, norm_w + (size_t)l * D_MODEL, hn, hn_b, D_MODEL);

        if (full) {
            const __bf16* inwb = in_w_b  + (size_t)l * 2 * D_INNER * D_MODEL;
            const __bf16* xpwb = xp_w_b  + (size_t)l * PROJ_LD * D_INNER;
            const __bf16* owb  = out_w_b + (size_t)l * D_MODEL * D_INNER;
            // xz = hn @ in_w^T   (512 x 3072, K=768)
            bgemm<<<dim3(2 * D_INNER / 64, NTOK / 64, 1), 256, 0, stream>>>(
                hn_b, D_MODEL, inwb, D_MODEL, xz, XZ_LD, NTOK, 2 * D_INNER, D_MODEL, D_MODEL, 0, nullptr);
            conv_silu<<<(NTOK * D_INNER + 255) / 256, 256, 0, stream>>>(xz, full_mask, cw, cb, xc, xcb, proj);
            // proj = xc @ xp_w^T  (512 x 80, K=1536), split-K z=4, atomicAdd into zeroed proj
            bgemm<<<dim3((PROJ_LD + 63) / 64, NTOK / 64, 4), 256, 0, stream>>>(
                xcb, D_INNER, xpwb, D_INNER, proj, PROJ_LD, NTOK, PROJ_LD, D_INNER, 384, 3, nullptr);
            // dt = softplus(proj[:, :48] @ dtp_w^T + dtp_b)  (K=48 -> fp32 path)
            mgemm<<<dim3(D_INNER / 64, NTOK / 64, 1), 256, 0, stream>>>(
                proj, PROJ_LD, dtw, DT_RANK, dt, D_INNER, NTOK, D_INNER, DT_RANK, DT_RANK, 1, dtb);
            scan_k<<<(BATCH * D_INNER + 255) / 256, 256, 0, stream>>>(xz, xc, proj, dt, Al, Dl, y, y_b);
            // h += y @ out_w^T  (split-K z=4, atomicAdd into residual h)
            bgemm<<<dim3(D_MODEL / 64, NTOK / 64, 4), 256, 0, stream>>>(
                y_b, D_INNER, owb, D_INNER, h, D_MODEL, NTOK, D_MODEL, D_INNER, 384, 3, nullptr);
        } else {
            const float* inw  = in_w  + (size_t)l * 2 * D_INNER * D_MODEL;
            const float* xpw  = xp_w  + (size_t)l * PROJ_LD * D_INNER;
            const float* ow   = out_w + (size_t)l * D_MODEL * D_INNER;
            mgemm<<<dim3(2 * D_INNER / 64, NTOK / 64, 1), 256, 0, stream>>>(
                hn, D_MODEL, inw, D_MODEL, xz, XZ_LD, NTOK, 2 * D_INNER, D_MODEL, D_MODEL, 0, nullptr);
            conv_silu<<<(NTOK * D_INNER + 255) / 256, 256, 0, stream>>>(xz, full_mask, cw, cb, xc, xcb, proj);
            mgemm<<<dim3((PROJ_LD + 63) / 64, NTOK / 64, 1), 256, 0, stream>>>(
                xc, D_INNER, xpw, D_INNER, proj, PROJ_LD, NTOK, PROJ_LD, D_INNER, D_INNER, 0, nullptr);
            mgemm<<<dim3(D_INNER / 64, NTOK / 64, 1), 256, 0, stream>>>(
                proj, PROJ_LD, dtw, DT_RANK, dt, D_INNER, NTOK, D_INNER, DT_RANK, DT_RANK, 1, dtb);
            scan_k<<<(BATCH * D_INNER + 255) / 256, 256, 0, stream>>>(xz, xc, proj, dt, Al, Dl, y, y_b);
            mgemm<<<dim3(D_MODEL / 64, NTOK / 64, 4), 256, 0, stream>>>(
                y, D_INNER, ow, D_INNER, h, D_MODEL, NTOK, D_MODEL, D_INNER, 384, 3, nullptr);
        }
    }

    rmsnorm_k<<<NTOK, 256, 0, stream>>>(h, norm_f_w, hn, hn_b, D_MODEL);
    // logits = hn @ embed^T  (512 x 50280, K=768)
    lgemm<<<dim3((VOCAB + 63) / 64, 2, 1), 256, 0, stream>>>(
        hn_b, D_MODEL, embed, D_MODEL, out, VOCAB, VOCAB, D_MODEL);
}